// Round 10
// baseline (449.473 us; speedup 1.0000x reference)
//
#include <hip/hip_runtime.h>
#include <math.h>

typedef __attribute__((ext_vector_type(8))) short short8v;
typedef __attribute__((ext_vector_type(4))) float float4v;
typedef unsigned int u32;
typedef unsigned short u16;

#define T_     2048
#define D_     400
#define H2_    400
#define MAXW_  10
#define M_     600
#define A_     100
#define FS_    20
#define HID_   150
#define HP_    160
#define MIN_   1220
#define KP_    1280
#define NCOL_  101
#define L2K_   192

#define NEGBIG_ (-1.0e30f)

// ---------------- workspace byte offsets ----------------
#define OB_MSC   8192u
#define OB_PM    10752u
#define OB_PA    394752u
#define OB_SPKC  778752u
#define OB_GB    780032u
#define OB_DC    780672u
#define OB_MSPK  787072u
#define OB_H1W   789632u
#define OB_MEBF  1173632u
#define OB_WSIM  2709632u
#define OB_WK2   3119232u
#define OB_W2A   4348032u
#define OB_END   4409472u

__device__ __forceinline__ float bflo(u32 u){ u32 v = u << 16; return __builtin_bit_cast(float, v); }
__device__ __forceinline__ float bfhi(u32 u){ u32 v = u & 0xFFFF0000u; return __builtin_bit_cast(float, v); }
__device__ __forceinline__ u16 f2bf(float f){
  u32 u = __builtin_bit_cast(u32, f);
  u32 r = (u + 0x7FFFu + ((u >> 16) & 1u)) >> 16;
  return (u16)r;
}
__device__ __forceinline__ u32 cvtpk(float lo, float hi){
  u32 r; asm("v_cvt_pk_bf16_f32 %0, %1, %2" : "=v"(r) : "v"(lo), "v"(hi)); return r;
}
// raw barrier: NO vmcnt drain (the whole point) — lgkm drained for ds visibility,
// sched_barrier + empty memory-clobber asm fence compiler motion (guide rule 18, m201 template)
__device__ __forceinline__ void barx(){
  asm volatile("s_waitcnt lgkmcnt(0)" ::: "memory");
  __builtin_amdgcn_sched_barrier(0);
  __builtin_amdgcn_s_barrier();
  __builtin_amdgcn_sched_barrier(0);
  asm volatile("" ::: "memory");
}

// ====== KB: fused weight prep — 5 transposes (with zero-pad) + consts ======
__global__ __launch_bounds__(256) void kb_prep(
    const float* __restrict__ msw1, const float* __restrict__ asw1,
    const float* __restrict__ asw2, const float* __restrict__ asb1,
    const float* __restrict__ spkt, const float* __restrict__ gent,
    const float* __restrict__ distt, const int* __restrict__ gid,
    u16* __restrict__ wsim, u16* __restrict__ wk2, u16* __restrict__ w2a,
    float* __restrict__ spk_c, float* __restrict__ gb, float* __restrict__ dc) {
  int z = blockIdx.z;
  if (z == 5) {
    if (blockIdx.x | blockIdx.y) return;
    int h = threadIdx.x;
    if (h >= HP_) return;
    if (h >= HID_) {
      spk_c[h] = 0.f; spk_c[HP_ + h] = 0.f; gb[h] = 0.f;
      for (int d = 0; d < 10; d++) dc[d * HP_ + h] = 0.f;
      return;
    }
    float s0 = 0.f, s1 = 0.f, g = asb1[h];
    int gi = gid[0];
    for (int f = 0; f < FS_; f++) {
      float w = asw1[(3660 + f) * HID_ + h];
      s0 += spkt[f] * w;
      s1 += spkt[FS_ + f] * w;
      g += gent[gi * FS_ + f] * asw1[(3680 + f) * HID_ + h];
    }
    spk_c[h] = s0; spk_c[HP_ + h] = s1; gb[h] = g;
    for (int d = 0; d < 10; d++) {
      float acc = 0.f;
      for (int f = 0; f < FS_; f++) acc += distt[d * FS_ + f] * asw1[(3700 + f) * HID_ + h];
      dc[d * HP_ + h] = acc;
    }
    return;
  }
  const float* src; u16* dst; int S, Rpad, R;
  if (z == 0)      { src = asw1 + 2440 * HID_; dst = wsim;            S = KP_;  Rpad = KP_;  R = MIN_; }
  else if (z == 1) { src = msw1;               dst = wk2;             S = KP_;  Rpad = KP_;  R = MIN_; }
  else if (z == 2) { src = asw1;               dst = wk2 + 160 * KP_; S = KP_;  Rpad = KP_;  R = MIN_; }
  else if (z == 3) { src = asw1 + 1220 * HID_; dst = wk2 + 320 * KP_; S = KP_;  Rpad = KP_;  R = MIN_; }
  else             { src = asw2;               dst = w2a;             S = L2K_; Rpad = L2K_; R = HID_;
                     if (blockIdx.x >= 6) return; }
  __shared__ float tile[32][33];
  int tx = threadIdx.x & 31, ty = threadIdx.x >> 5;
  int rb = blockIdx.x * 32, cb = blockIdx.y * 32;
#pragma unroll
  for (int it = 0; it < 4; it++) {
    int r = rb + ty + it * 8, c = cb + tx;
    tile[ty + it * 8][tx] = (r < R && c < HID_) ? src[(size_t)r * HID_ + c] : 0.f;
  }
  __syncthreads();
#pragma unroll
  for (int it = 0; it < 4; it++) {
    int c = cb + ty + it * 8, r = rb + tx;
    if (c < HP_ && r < Rpad) dst[(size_t)c * S + r] = f2bf(tile[tx][ty + it * 8]);
  }
}

// ====== KA: mention embeddings (head-logits fused) ======
__global__ __launch_bounds__(256) void ka_ment_emb(
    const float* __restrict__ doc, const float* __restrict__ lstm,
    const int* __restrict__ cs, const int* __restrict__ ce,
    const int* __restrict__ tmi, const int* __restrict__ spk,
    const float* __restrict__ wtab, const float* __restrict__ Wsp,
    const float* __restrict__ bsp,
    u16* __restrict__ mebf, int* __restrict__ mspk) {
  __shared__ float sl[MAXW_];
  int b = blockIdx.x, tid = threadIdx.x;
  int idx = tmi[b];
  int s = cs[idx], e = ce[idx];
  int width = e - s + 1;
  int wv = tid >> 6, lane = tid & 63;
  for (int w = wv; w < width; w += 4) {
    float acc = 0.f;
    for (int k = lane; k < H2_; k += 64) acc += lstm[(s + w) * H2_ + k] * Wsp[k];
    for (int off = 32; off; off >>= 1) acc += __shfl_down(acc, off);
    if (lane == 0) sl[w] = acc + bsp[0];
  }
  u16* row = mebf + (size_t)b * KP_;
  for (int d = tid; d < D_; d += 256) {
    row[d]      = f2bf(lstm[s * H2_ + d]);
    row[D_ + d] = f2bf(lstm[e * H2_ + d]);
  }
  if (tid < FS_) row[2 * D_ + tid] = f2bf(wtab[(width - 1) * FS_ + tid]);
  for (int d = tid; d < (KP_ - MIN_); d += 256) row[MIN_ + d] = 0;
  __syncthreads();
  float wl[MAXW_];
  float mx = -1e30f;
  for (int w = 0; w < width; w++) { wl[w] = sl[w]; mx = fmaxf(mx, wl[w]); }
  float sum = 0.f;
  for (int w = 0; w < width; w++) { wl[w] = expf(wl[w] - mx); sum += wl[w]; }
  float inv = 1.f / sum;
  for (int d = tid; d < D_; d += 256) {
    float acc = 0.f;
    for (int w = 0; w < width; w++) acc += wl[w] * doc[(s + w) * D_ + d];
    row[2 * D_ + FS_ + d] = f2bf(acc * inv);
  }
  if (tid == 0) mspk[b] = spk[s];
}

// ====== K2: mention-side GEMM, B staged in LDS per k-tile ======
__global__ __launch_bounds__(256) void k2_mfma(
    const u16* __restrict__ mebf, const u16* __restrict__ wk2,
    const float* __restrict__ msb1,
    float* __restrict__ h1w, float* __restrict__ Pm, float* __restrict__ Pa) {
  __shared__ __align__(16) char lds[20480];
  int mt = blockIdx.x, ct = blockIdx.y;
  int tid = threadIdx.x, w = tid >> 6, l = tid & 63, l15 = l & 15, oct = l >> 4;
  int m0 = mt * 128;
  const u16* Bb = wk2 + (size_t)ct * 160 * KP_;
  u32 aswz = (u32)(l15 & 7) << 4;
  float4v acc[2][10];
#pragma unroll
  for (int p = 0; p < 2; p++)
#pragma unroll
    for (int h = 0; h < 10; h++) acc[p][h] = (float4v)0.f;
  int arow[2];
#pragma unroll
  for (int p = 0; p < 2; p++) {
    int r = m0 + (2 * w + p) * 16 + l15;
    arow[p] = (r < M_) ? r : (M_ - 1);
  }
  for (int kt = 0; kt < 20; kt++) {
    int k0 = kt * 64;
#pragma unroll
    for (int it = 0; it < 5; it++) {
      int ee = tid + it * 256;
      int r = ee >> 3, sg = ee & 7;
      uint4 v = *(const uint4*)(Bb + (size_t)r * KP_ + k0 + sg * 8);
      *(uint4*)(lds + (u32)(r * 128) + (((u32)(sg * 16)) ^ ((u32)(r & 7) << 4))) = v;
    }
    short8v A[2][2];
#pragma unroll
    for (int p = 0; p < 2; p++)
#pragma unroll
      for (int ks2 = 0; ks2 < 2; ks2++)
        A[p][ks2] = *(const short8v*)(mebf + (size_t)arow[p] * KP_ + k0 + ks2 * 32 + oct * 8);
    __syncthreads();
#pragma unroll
    for (int ks2 = 0; ks2 < 2; ks2++) {
      u32 inner = ((u32)(ks2 * 64 + oct * 16)) ^ aswz;
#pragma unroll
      for (int hf = 0; hf < 10; hf++) {
        short8v B = *(const short8v*)(lds + (u32)((hf * 16 + l15) * 128) + inner);
        acc[0][hf] = __builtin_amdgcn_mfma_f32_16x16x32_bf16(A[0][ks2], B, acc[0][hf], 0, 0, 0);
        acc[1][hf] = __builtin_amdgcn_mfma_f32_16x16x32_bf16(A[1][ks2], B, acc[1][hf], 0, 0, 0);
      }
    }
    __syncthreads();
  }
#pragma unroll
  for (int p = 0; p < 2; p++) {
    int mb = m0 + (2 * w + p) * 16 + oct * 4;
#pragma unroll
    for (int hf = 0; hf < 10; hf++) {
      int c = hf * 16 + l15;
#pragma unroll
      for (int r = 0; r < 4; r++) {
        int m = mb + r;
        if (m < M_) {
          float v = acc[p][hf][r];
          if (ct == 0) {
            float bias = (c < HID_) ? msb1[c] : 0.f;
            h1w[m * HP_ + c] = fmaxf(v + bias, 0.f);
          } else if (ct == 1) {
            Pm[m * HP_ + c] = v;
          } else {
            Pa[m * HP_ + c] = v;
          }
        }
      }
    }
  }
}

// ====== K5: mention scorer layers 2+3 ======
__global__ __launch_bounds__(256) void k5_msc(
    const float* __restrict__ h1w, const float* __restrict__ w2, const float* __restrict__ b2,
    const float* __restrict__ w3, const float* __restrict__ b3, float* __restrict__ msc) {
  __shared__ float h1s[HID_];
  __shared__ float h2s[HID_];
  __shared__ float red[4];
  int i = blockIdx.x, tid = threadIdx.x;
  if (tid < HID_) h1s[tid] = h1w[i * HP_ + tid];
  __syncthreads();
  if (tid < HID_) {
    float a = b2[tid];
    for (int k = 0; k < HID_; k++) a += h1s[k] * w2[k * HID_ + tid];
    h2s[tid] = fmaxf(a, 0.f);
  }
  __syncthreads();
  float p = (tid < HID_) ? h2s[tid] * w3[tid] : 0.f;
  for (int off = 32; off; off >>= 1) p += __shfl_down(p, off, 64);
  if ((tid & 63) == 0) red[tid >> 6] = p;
  __syncthreads();
  if (tid == 0) msc[i] = red[0] + red[1] + red[2] + red[3] + b3[0];
}

// ====== K4: pair kernel — pipelined k-loop (raw barriers, no vmcnt drain) ======
// LDS: B[160][128B] @0 (20KB) | P[128][128B] @20480 (16KB) | e_i @36864 (2.5KB)
// finalize overlay: h1t 3x16KB @0 (48KB)
__global__ __launch_bounds__(256) void k4_pairs(
    const u16* __restrict__ mebf, const u16* __restrict__ wsim, const u16* __restrict__ w2a,
    const float* __restrict__ Pm, const float* __restrict__ Pa,
    const float* __restrict__ spkc, const float* __restrict__ gb, const float* __restrict__ dc,
    const int* __restrict__ mspk, const int* __restrict__ bins,
    const float* __restrict__ msc,
    const float* __restrict__ ab2, const float* __restrict__ aw3, const float* __restrict__ ab3,
    float* __restrict__ out) {
  __shared__ __align__(16) char lds[49152];
  int bid = blockIdx.x;
  int i = (bid & 7) * 75 + (bid >> 3);    // XCD-chunked swizzle, bijective (600 = 8*75)
  int tid = threadIdx.x, w = tid >> 6, l = tid & 63, l15 = l & 15, oct = l >> 4;
  int len = min(i, A_);
  int jbase = max(i - A_, 0);
  if (len == 0) {
    if (tid == 0) out[0] = 0.f;
    if (tid < A_) out[1 + tid] = NEGBIG_;
    return;
  }
  // stage e_i
  {
    const uint4* src = (const uint4*)(mebf + (size_t)i * KP_);
    uint4* dst = (uint4*)(lds + 36864);
    if (tid < 160) dst[tid] = src[tid];
  }
  __syncthreads();

  float4v acc[2][10];
#pragma unroll
  for (int p = 0; p < 2; p++)
#pragma unroll
    for (int h = 0; h < 10; h++) acc[p][h] = (float4v)0.f;

  int arow = tid >> 1;
  int khe = (tid & 1) * 32;
  int jrow = min(jbase + arow, M_ - 1);
  const u16* ejrow = mebf + (size_t)jrow * KP_;
  u32 pwr_base = 20480u + (u32)arow * 128u;
  u32 pwr_swz  = (u32)(arow & 7) << 4;
  u32 kh2 = (u32)khe * 2u;
  int r0 = 2 * w * 16 + l15, r1 = r0 + 16;
  u32 aswz = (u32)(l15 & 7) << 4;
  // B-stage addressing (constant per thread)
  int bsr = tid >> 3, bssg = tid & 7;               // it-chunk row/slot bases
  // pipeline registers: B tile (5x16B) and e_j fragment (4x16B)
  uint4 pb[5], pe[4];

  // ---- prologue: load tile 0 into regs ----
#pragma unroll
  for (int it = 0; it < 5; it++) {
    int ee = tid + it * 256;
    int r = ee >> 3, sg = ee & 7;
    pb[it] = *(const uint4*)(wsim + (size_t)r * KP_ + sg * 8);
  }
#pragma unroll
  for (int q = 0; q < 4; q++) pe[q] = *(const uint4*)(ejrow + khe + q * 8);
  // write B(0) (auto vmcnt waits), P-build(0)
#pragma unroll
  for (int it = 0; it < 5; it++) {
    int ee = tid + it * 256;
    int r = ee >> 3, sg = ee & 7;
    *(uint4*)(lds + (u32)(r * 128) + (((u32)(sg * 16)) ^ ((u32)(r & 7) << 4))) = pb[it];
  }
  {
    const uint4* eis = (const uint4*)((const u16*)(lds + 36864) + khe);
#pragma unroll
    for (int q = 0; q < 4; q++) {
      uint4 ej = pe[q];
      uint4 ei = eis[q];
      const u32* pj = (const u32*)&ej;
      const u32* pi = (const u32*)&ei;
      u32 o[4];
#pragma unroll
      for (int c = 0; c < 4; c++)
        o[c] = cvtpk(bflo(pj[c]) * bflo(pi[c]), bfhi(pj[c]) * bfhi(pi[c]));
      *(uint4*)(lds + (pwr_base + ((kh2 + (u32)q * 16u) ^ pwr_swz))) = make_uint4(o[0], o[1], o[2], o[3]);
    }
  }
  // issue loads for tile 1 (stay in flight across barrier + MFMA phase)
#pragma unroll
  for (int q = 0; q < 4; q++) pe[q] = *(const uint4*)(ejrow + 64 + khe + q * 8);
#pragma unroll
  for (int it = 0; it < 5; it++) {
    int ee = tid + it * 256;
    int r = ee >> 3, sg = ee & 7;
    pb[it] = *(const uint4*)(wsim + (size_t)r * KP_ + 64 + sg * 8);
  }
  barx();

  // ---- pipelined k-loop: 2 raw barriers / tile, loads fly one phase ahead ----
  for (int kt = 0; kt < 20; kt++) {
    // (f) MFMA phase: pure LDS reads
#pragma unroll
    for (int ks2 = 0; ks2 < 2; ks2++) {
      u32 inner = ((u32)(ks2 * 64 + oct * 16)) ^ aswz;
      short8v A0 = *(const short8v*)(lds + 20480u + (u32)r0 * 128u + inner);
      short8v A1 = *(const short8v*)(lds + 20480u + (u32)r1 * 128u + inner);
#pragma unroll
      for (int hf = 0; hf < 10; hf++) {
        short8v B = *(const short8v*)(lds + (u32)((hf * 16 + l15) * 128) + inner);
        acc[0][hf] = __builtin_amdgcn_mfma_f32_16x16x32_bf16(A0, B, acc[0][hf], 0, 0, 0);
        acc[1][hf] = __builtin_amdgcn_mfma_f32_16x16x32_bf16(A1, B, acc[1][hf], 0, 0, 0);
      }
    }
    barx();                                  // (g) all waves done reading B,P
    if (kt < 19) {
      // (b) write B(kt+1) from regs (compiler inserts exact vmcnt waits)
#pragma unroll
      for (int it = 0; it < 5; it++) {
        int ee = tid + it * 256;
        int r = ee >> 3, sg = ee & 7;
        *(uint4*)(lds + (u32)(r * 128) + (((u32)(sg * 16)) ^ ((u32)(r & 7) << 4))) = pb[it];
      }
      // P-build(kt+1)
      {
        int k0n = (kt + 1) * 64;
        const uint4* eis = (const uint4*)((const u16*)(lds + 36864) + k0n + khe);
#pragma unroll
        for (int q = 0; q < 4; q++) {
          uint4 ej = pe[q];
          uint4 ei = eis[q];
          const u32* pj = (const u32*)&ej;
          const u32* pi = (const u32*)&ei;
          u32 o[4];
#pragma unroll
          for (int c = 0; c < 4; c++)
            o[c] = cvtpk(bflo(pj[c]) * bflo(pi[c]), bfhi(pj[c]) * bfhi(pi[c]));
          *(uint4*)(lds + (pwr_base + ((kh2 + (u32)q * 16u) ^ pwr_swz))) = make_uint4(o[0], o[1], o[2], o[3]);
        }
      }
      // (d) issue loads for kt+2
      if (kt < 18) {
        int k2o = (kt + 2) * 64;
#pragma unroll
        for (int q = 0; q < 4; q++) pe[q] = *(const uint4*)(ejrow + k2o + khe + q * 8);
#pragma unroll
        for (int it = 0; it < 5; it++) {
          int ee = tid + it * 256;
          int r = ee >> 3, sg = ee & 7;
          pb[it] = *(const uint4*)(wsim + (size_t)r * KP_ + k2o + sg * 8);
        }
      }
      barx();                                // (e) B,P for kt+1 visible
    }
  }
  (void)bsr; (void)bssg;

  // ---- finalize: h1 -> h1t bf16 swizzled (overlay; all k-loop reads done) ----
  __syncthreads();
  for (int x = tid; x < 2048; x += 256) {
    int a = x >> 4, q = x & 15;
    u32 byte = 32768u + (u32)a * 128u + (((u32)(64 + q * 4)) ^ ((u32)(a & 7) << 4));
    *(u32*)(lds + byte) = 0u;
  }
  int mi = mspk[i];
#pragma unroll
  for (int hf = 0; hf < 10; hf++) {
    int h = hf * 16 + l15;
    float pmh = Pm[i * HP_ + h];
    float gbh = gb[h];
    int t = h >> 6, kkb = (h & 63) * 2;
#pragma unroll
    for (int p = 0; p < 2; p++) {
      int ab = (2 * w + p) * 16 + oct * 4;
#pragma unroll
      for (int r = 0; r < 4; r++) {
        int a = ab + r;
        int ju = jbase + a;
        int jr = min(ju, M_ - 1);
        int same = (mspk[jr] == mi) ? 1 : 0;
        int dist = min(max(i - ju, 0), 64);
        int bin = bins[dist];
        float v = acc[p][hf][r] + pmh + gbh + Pa[jr * HP_ + h]
                + spkc[same * HP_ + h] + dc[bin * HP_ + h];
        v = fmaxf(v, 0.f);
        u32 byte = (u32)t * 16384u + (u32)a * 128u + (((u32)kkb) ^ ((u32)(a & 7) << 4));
        *(u16*)(lds + byte) = f2bf(v);
      }
    }
  }
  __syncthreads();

  // ---- layer 2 via MFMA (K=192) ----
  float4v b2acc[2][10];
#pragma unroll
  for (int p = 0; p < 2; p++)
#pragma unroll
    for (int h = 0; h < 10; h++) b2acc[p][h] = (float4v)0.f;
#pragma unroll
  for (int t = 0; t < 3; t++) {
#pragma unroll
    for (int ks2 = 0; ks2 < 2; ks2++) {
      u32 inner = ((u32)(ks2 * 64 + oct * 16)) ^ aswz;
      u32 tb = (u32)t * 16384u;
      short8v A0 = *(const short8v*)(lds + tb + (u32)r0 * 128u + inner);
      short8v A1 = *(const short8v*)(lds + tb + (u32)r1 * 128u + inner);
      int ke = t * 64 + ks2 * 32 + oct * 8;
#pragma unroll
      for (int hf = 0; hf < 10; hf++) {
        short8v B = *(const short8v*)(w2a + (size_t)(hf * 16 + l15) * L2K_ + ke);
        b2acc[0][hf] = __builtin_amdgcn_mfma_f32_16x16x32_bf16(A0, B, b2acc[0][hf], 0, 0, 0);
        b2acc[1][hf] = __builtin_amdgcn_mfma_f32_16x16x32_bf16(A1, B, b2acc[1][hf], 0, 0, 0);
      }
    }
  }

  // ---- layer 3 + mask + mention scores ----
  float part[2][4] = {{0.f,0.f,0.f,0.f},{0.f,0.f,0.f,0.f}};
#pragma unroll
  for (int hf = 0; hf < 10; hf++) {
    int h = hf * 16 + l15;
    float bias = (h < HID_) ? ab2[h] : 0.f;
    float w3v  = (h < HID_) ? aw3[h] : 0.f;
#pragma unroll
    for (int p = 0; p < 2; p++)
#pragma unroll
      for (int r = 0; r < 4; r++) {
        float hv = fmaxf(b2acc[p][hf][r] + bias, 0.f);
        part[p][r] += hv * w3v;
      }
  }
#pragma unroll
  for (int m = 1; m <= 8; m <<= 1) {
#pragma unroll
    for (int p = 0; p < 2; p++)
#pragma unroll
      for (int r = 0; r < 4; r++) part[p][r] += __shfl_xor(part[p][r], m, 64);
  }
  float b3 = ab3[0];
  float msci = msc[i];
  if (l15 == 0) {
#pragma unroll
    for (int p = 0; p < 2; p++)
#pragma unroll
      for (int r = 0; r < 4; r++) {
        int a = (2 * w + p) * 16 + oct * 4 + r;
        if (a < A_) {
          float res = (a < len) ? (part[p][r] + b3 + msci + msc[jbase + a]) : NEGBIG_;
          out[(size_t)i * NCOL_ + 1 + a] = res;
        }
      }
  }
  if (tid == 0) out[(size_t)i * NCOL_] = 0.f;
}

extern "C" void kernel_launch(void* const* d_in, const int* in_sizes, int n_in,
                              void* d_out, int out_size, void* d_ws, size_t ws_size,
                              hipStream_t stream) {
  const float* doc   = (const float*)d_in[0];
  const float* lstm  = (const float*)d_in[1];
  const int*   cs    = (const int*)d_in[2];
  const int*   ce    = (const int*)d_in[3];
  const int*   tmi   = (const int*)d_in[4];
  const int*   spk   = (const int*)d_in[7];
  const int*   gid   = (const int*)d_in[8];
  const int*   bins  = (const int*)d_in[9];
  const float* wtab  = (const float*)d_in[10];
  const float* spkt  = (const float*)d_in[11];
  const float* gent  = (const float*)d_in[12];
  const float* distt = (const float*)d_in[13];
  const float* Wsp   = (const float*)d_in[14];
  const float* bsp   = (const float*)d_in[15];
  const float* msw1  = (const float*)d_in[16];
  const float* msb1  = (const float*)d_in[17];
  const float* msw2  = (const float*)d_in[18];
  const float* msb2  = (const float*)d_in[19];
  const float* msw3  = (const float*)d_in[20];
  const float* msb3  = (const float*)d_in[21];
  const float* asw1  = (const float*)d_in[22];
  const float* asb1  = (const float*)d_in[23];
  const float* asw2  = (const float*)d_in[24];
  const float* asb2  = (const float*)d_in[25];
  const float* asw3  = (const float*)d_in[26];
  const float* asb3  = (const float*)d_in[27];
  (void)in_sizes; (void)n_in; (void)out_size; (void)ws_size;

  char* ws = (char*)d_ws;
  float* msc   = (float*)(ws + OB_MSC);
  float* Pm    = (float*)(ws + OB_PM);
  float* Pa    = (float*)(ws + OB_PA);
  float* spkc  = (float*)(ws + OB_SPKC);
  float* gb    = (float*)(ws + OB_GB);
  float* dc    = (float*)(ws + OB_DC);
  int*   mspk  = (int*)(ws + OB_MSPK);
  float* h1w   = (float*)(ws + OB_H1W);
  u16*   mebf  = (u16*)(ws + OB_MEBF);
  u16*   wsim  = (u16*)(ws + OB_WSIM);
  u16*   wk2   = (u16*)(ws + OB_WK2);
  u16*   w2a   = (u16*)(ws + OB_W2A);
  float* out   = (float*)d_out;

  dim3 gb_(40, 5, 6);
  kb_prep<<<gb_, 256, 0, stream>>>(msw1, asw1, asw2, asb1, spkt, gent, distt, gid,
                                   wsim, wk2, w2a, spkc, gb, dc);
  ka_ment_emb<<<M_, 256, 0, stream>>>(doc, lstm, cs, ce, tmi, spk, wtab, Wsp, bsp,
                                      mebf, mspk);
  dim3 g2(5, 3);
  k2_mfma<<<g2, 256, 0, stream>>>(mebf, wk2, msb1, h1w, Pm, Pa);
  k5_msc<<<M_, 256, 0, stream>>>(h1w, msw2, msb2, msw3, msb3, msc);
  k4_pairs<<<M_, 256, 0, stream>>>(mebf, wsim, w2a, Pm, Pa, spkc, gb, dc,
                                   mspk, bins, msc, asb2, asw3, asb3, out);
}

// Round 11
// 359.716 us; speedup vs baseline: 1.2495x; 1.2495x over previous
//
#include <hip/hip_runtime.h>
#include <math.h>

typedef __attribute__((ext_vector_type(8))) short short8v;
typedef __attribute__((ext_vector_type(4))) float float4v;
typedef unsigned int u32;
typedef unsigned short u16;

#define T_     2048
#define D_     400
#define H2_    400
#define MAXW_  10
#define M_     600
#define A_     100
#define FS_    20
#define HID_   150
#define HP_    160
#define MIN_   1220
#define KP_    1280
#define NCOL_  101
#define L2K_   192

#define NEGBIG_ (-1.0e30f)

// k4 LDS layout: B0 | B1 | P | e_i   (finalize overlays [0,49152) with h1t)
#define LB0_  0u
#define LB1_  20480u
#define LP_   40960u
#define LEI_  57344u

// ---------------- workspace byte offsets ----------------
#define OB_MSC   8192u
#define OB_PM    10752u
#define OB_PA    394752u
#define OB_SPKC  778752u
#define OB_GB    780032u
#define OB_DC    780672u
#define OB_MSPK  787072u
#define OB_H1W   789632u
#define OB_MEBF  1173632u
#define OB_WSIM  2709632u
#define OB_WK2   3119232u
#define OB_W2A   4348032u
#define OB_END   4409472u

__device__ __forceinline__ float bflo(u32 u){ u32 v = u << 16; return __builtin_bit_cast(float, v); }
__device__ __forceinline__ float bfhi(u32 u){ u32 v = u & 0xFFFF0000u; return __builtin_bit_cast(float, v); }
__device__ __forceinline__ u16 f2bf(float f){
  u32 u = __builtin_bit_cast(u32, f);
  u32 r = (u + 0x7FFFu + ((u >> 16) & 1u)) >> 16;
  return (u16)r;
}
__device__ __forceinline__ u32 cvtpk(float lo, float hi){
  u32 r; asm("v_cvt_pk_bf16_f32 %0, %1, %2" : "=v"(r) : "v"(lo), "v"(hi)); return r;
}
// global->LDS DMA, 16B/lane; LDS dest = wave-uniform base + lane*16, global src per-lane
__device__ __forceinline__ void gload_lds16(const u16* g, char* l){
  __builtin_amdgcn_global_load_lds((const __attribute__((address_space(1))) void*)g,
                                   (__attribute__((address_space(3))) void*)l, 16, 0, 0);
}

// ====== KB: fused weight prep — 5 transposes (with zero-pad) + consts ======
__global__ __launch_bounds__(256) void kb_prep(
    const float* __restrict__ msw1, const float* __restrict__ asw1,
    const float* __restrict__ asw2, const float* __restrict__ asb1,
    const float* __restrict__ spkt, const float* __restrict__ gent,
    const float* __restrict__ distt, const int* __restrict__ gid,
    u16* __restrict__ wsim, u16* __restrict__ wk2, u16* __restrict__ w2a,
    float* __restrict__ spk_c, float* __restrict__ gb, float* __restrict__ dc) {
  int z = blockIdx.z;
  if (z == 5) {
    if (blockIdx.x | blockIdx.y) return;
    int h = threadIdx.x;
    if (h >= HP_) return;
    if (h >= HID_) {
      spk_c[h] = 0.f; spk_c[HP_ + h] = 0.f; gb[h] = 0.f;
      for (int d = 0; d < 10; d++) dc[d * HP_ + h] = 0.f;
      return;
    }
    float s0 = 0.f, s1 = 0.f, g = asb1[h];
    int gi = gid[0];
    for (int f = 0; f < FS_; f++) {
      float w = asw1[(3660 + f) * HID_ + h];
      s0 += spkt[f] * w;
      s1 += spkt[FS_ + f] * w;
      g += gent[gi * FS_ + f] * asw1[(3680 + f) * HID_ + h];
    }
    spk_c[h] = s0; spk_c[HP_ + h] = s1; gb[h] = g;
    for (int d = 0; d < 10; d++) {
      float acc = 0.f;
      for (int f = 0; f < FS_; f++) acc += distt[d * FS_ + f] * asw1[(3700 + f) * HID_ + h];
      dc[d * HP_ + h] = acc;
    }
    return;
  }
  const float* src; u16* dst; int S, Rpad, R;
  if (z == 0)      { src = asw1 + 2440 * HID_; dst = wsim;            S = KP_;  Rpad = KP_;  R = MIN_; }
  else if (z == 1) { src = msw1;               dst = wk2;             S = KP_;  Rpad = KP_;  R = MIN_; }
  else if (z == 2) { src = asw1;               dst = wk2 + 160 * KP_; S = KP_;  Rpad = KP_;  R = MIN_; }
  else if (z == 3) { src = asw1 + 1220 * HID_; dst = wk2 + 320 * KP_; S = KP_;  Rpad = KP_;  R = MIN_; }
  else             { src = asw2;               dst = w2a;             S = L2K_; Rpad = L2K_; R = HID_;
                     if (blockIdx.x >= 6) return; }
  __shared__ float tile[32][33];
  int tx = threadIdx.x & 31, ty = threadIdx.x >> 5;
  int rb = blockIdx.x * 32, cb = blockIdx.y * 32;
#pragma unroll
  for (int it = 0; it < 4; it++) {
    int r = rb + ty + it * 8, c = cb + tx;
    tile[ty + it * 8][tx] = (r < R && c < HID_) ? src[(size_t)r * HID_ + c] : 0.f;
  }
  __syncthreads();
#pragma unroll
  for (int it = 0; it < 4; it++) {
    int c = cb + ty + it * 8, r = rb + tx;
    if (c < HP_ && r < Rpad) dst[(size_t)c * S + r] = f2bf(tile[tx][ty + it * 8]);
  }
}

// ====== KA: mention embeddings (head-logits fused) ======
__global__ __launch_bounds__(256) void ka_ment_emb(
    const float* __restrict__ doc, const float* __restrict__ lstm,
    const int* __restrict__ cs, const int* __restrict__ ce,
    const int* __restrict__ tmi, const int* __restrict__ spk,
    const float* __restrict__ wtab, const float* __restrict__ Wsp,
    const float* __restrict__ bsp,
    u16* __restrict__ mebf, int* __restrict__ mspk) {
  __shared__ float sl[MAXW_];
  int b = blockIdx.x, tid = threadIdx.x;
  int idx = tmi[b];
  int s = cs[idx], e = ce[idx];
  int width = e - s + 1;
  int wv = tid >> 6, lane = tid & 63;
  for (int w = wv; w < width; w += 4) {
    float acc = 0.f;
    for (int k = lane; k < H2_; k += 64) acc += lstm[(s + w) * H2_ + k] * Wsp[k];
    for (int off = 32; off; off >>= 1) acc += __shfl_down(acc, off);
    if (lane == 0) sl[w] = acc + bsp[0];
  }
  u16* row = mebf + (size_t)b * KP_;
  for (int d = tid; d < D_; d += 256) {
    row[d]      = f2bf(lstm[s * H2_ + d]);
    row[D_ + d] = f2bf(lstm[e * H2_ + d]);
  }
  if (tid < FS_) row[2 * D_ + tid] = f2bf(wtab[(width - 1) * FS_ + tid]);
  for (int d = tid; d < (KP_ - MIN_); d += 256) row[MIN_ + d] = 0;
  __syncthreads();
  float wl[MAXW_];
  float mx = -1e30f;
  for (int w = 0; w < width; w++) { wl[w] = sl[w]; mx = fmaxf(mx, wl[w]); }
  float sum = 0.f;
  for (int w = 0; w < width; w++) { wl[w] = expf(wl[w] - mx); sum += wl[w]; }
  float inv = 1.f / sum;
  for (int d = tid; d < D_; d += 256) {
    float acc = 0.f;
    for (int w = 0; w < width; w++) acc += wl[w] * doc[(s + w) * D_ + d];
    row[2 * D_ + FS_ + d] = f2bf(acc * inv);
  }
  if (tid == 0) mspk[b] = spk[s];
}

// ====== K2: mention-side GEMM, B staged in LDS per k-tile ======
__global__ __launch_bounds__(256) void k2_mfma(
    const u16* __restrict__ mebf, const u16* __restrict__ wk2,
    const float* __restrict__ msb1,
    float* __restrict__ h1w, float* __restrict__ Pm, float* __restrict__ Pa) {
  __shared__ __align__(16) char lds[20480];
  int mt = blockIdx.x, ct = blockIdx.y;
  int tid = threadIdx.x, w = tid >> 6, l = tid & 63, l15 = l & 15, oct = l >> 4;
  int m0 = mt * 128;
  const u16* Bb = wk2 + (size_t)ct * 160 * KP_;
  u32 aswz = (u32)(l15 & 7) << 4;
  float4v acc[2][10];
#pragma unroll
  for (int p = 0; p < 2; p++)
#pragma unroll
    for (int h = 0; h < 10; h++) acc[p][h] = (float4v)0.f;
  int arow[2];
#pragma unroll
  for (int p = 0; p < 2; p++) {
    int r = m0 + (2 * w + p) * 16 + l15;
    arow[p] = (r < M_) ? r : (M_ - 1);
  }
  for (int kt = 0; kt < 20; kt++) {
    int k0 = kt * 64;
#pragma unroll
    for (int it = 0; it < 5; it++) {
      int ee = tid + it * 256;
      int r = ee >> 3, sg = ee & 7;
      uint4 v = *(const uint4*)(Bb + (size_t)r * KP_ + k0 + sg * 8);
      *(uint4*)(lds + (u32)(r * 128) + (((u32)(sg * 16)) ^ ((u32)(r & 7) << 4))) = v;
    }
    short8v A[2][2];
#pragma unroll
    for (int p = 0; p < 2; p++)
#pragma unroll
      for (int ks2 = 0; ks2 < 2; ks2++)
        A[p][ks2] = *(const short8v*)(mebf + (size_t)arow[p] * KP_ + k0 + ks2 * 32 + oct * 8);
    __syncthreads();
#pragma unroll
    for (int ks2 = 0; ks2 < 2; ks2++) {
      u32 inner = ((u32)(ks2 * 64 + oct * 16)) ^ aswz;
#pragma unroll
      for (int hf = 0; hf < 10; hf++) {
        short8v B = *(const short8v*)(lds + (u32)((hf * 16 + l15) * 128) + inner);
        acc[0][hf] = __builtin_amdgcn_mfma_f32_16x16x32_bf16(A[0][ks2], B, acc[0][hf], 0, 0, 0);
        acc[1][hf] = __builtin_amdgcn_mfma_f32_16x16x32_bf16(A[1][ks2], B, acc[1][hf], 0, 0, 0);
      }
    }
    __syncthreads();
  }
#pragma unroll
  for (int p = 0; p < 2; p++) {
    int mb = m0 + (2 * w + p) * 16 + oct * 4;
#pragma unroll
    for (int hf = 0; hf < 10; hf++) {
      int c = hf * 16 + l15;
#pragma unroll
      for (int r = 0; r < 4; r++) {
        int m = mb + r;
        if (m < M_) {
          float v = acc[p][hf][r];
          if (ct == 0) {
            float bias = (c < HID_) ? msb1[c] : 0.f;
            h1w[m * HP_ + c] = fmaxf(v + bias, 0.f);
          } else if (ct == 1) {
            Pm[m * HP_ + c] = v;
          } else {
            Pa[m * HP_ + c] = v;
          }
        }
      }
    }
  }
}

// ====== K5: mention scorer layers 2+3 ======
__global__ __launch_bounds__(256) void k5_msc(
    const float* __restrict__ h1w, const float* __restrict__ w2, const float* __restrict__ b2,
    const float* __restrict__ w3, const float* __restrict__ b3, float* __restrict__ msc) {
  __shared__ float h1s[HID_];
  __shared__ float h2s[HID_];
  __shared__ float red[4];
  int i = blockIdx.x, tid = threadIdx.x;
  if (tid < HID_) h1s[tid] = h1w[i * HP_ + tid];
  __syncthreads();
  if (tid < HID_) {
    float a = b2[tid];
    for (int k = 0; k < HID_; k++) a += h1s[k] * w2[k * HID_ + tid];
    h2s[tid] = fmaxf(a, 0.f);
  }
  __syncthreads();
  float p = (tid < HID_) ? h2s[tid] * w3[tid] : 0.f;
  for (int off = 32; off; off >>= 1) p += __shfl_down(p, off, 64);
  if ((tid & 63) == 0) red[tid >> 6] = p;
  __syncthreads();
  if (tid == 0) msc[i] = red[0] + red[1] + red[2] + red[3] + b3[0];
}

// ====== K4: pair kernel — global_load_lds DMA + dbuf B + 1 barrier/tile ======
// B is staged to a LINEAR LDS layout via DMA with pre-swizzled GLOBAL source
// (rule 21); P rows are wave-private (wave w builds+reads rows [32w,32w+32)).
__global__ __launch_bounds__(256) void k4_pairs(
    const u16* __restrict__ mebf, const u16* __restrict__ wsim, const u16* __restrict__ w2a,
    const float* __restrict__ Pm, const float* __restrict__ Pa,
    const float* __restrict__ spkc, const float* __restrict__ gb, const float* __restrict__ dc,
    const int* __restrict__ mspk, const int* __restrict__ bins,
    const float* __restrict__ msc,
    const float* __restrict__ ab2, const float* __restrict__ aw3, const float* __restrict__ ab3,
    float* __restrict__ out) {
  __shared__ __align__(16) char lds[59904];
  int bid = blockIdx.x;
  int i = (bid & 7) * 75 + (bid >> 3);    // XCD-chunked swizzle, bijective (600 = 8*75)
  int tid = threadIdx.x, w = tid >> 6, l = tid & 63, l15 = l & 15, oct = l >> 4;
  int len = min(i, A_);
  int jbase = max(i - A_, 0);
  if (len == 0) {
    if (tid == 0) out[0] = 0.f;
    if (tid < A_) out[1 + tid] = NEGBIG_;
    return;
  }
  // stage e_i
  {
    const uint4* src = (const uint4*)(mebf + (size_t)i * KP_);
    uint4* dst = (uint4*)(lds + LEI_);
    if (tid < 160) dst[tid] = src[tid];
  }
  __syncthreads();

  float4v acc[2][10];
#pragma unroll
  for (int p = 0; p < 2; p++)
#pragma unroll
    for (int h = 0; h < 10; h++) acc[p][h] = (float4v)0.f;

  int arow = tid >> 1;                       // wave w owns P rows [32w,32w+32)
  int khe = (tid & 1) * 32;
  int jrow = min(jbase + arow, M_ - 1);
  const u16* ejrow = mebf + (size_t)jrow * KP_;
  u32 pwr_base = LP_ + (u32)arow * 128u;
  u32 pwr_swz  = (u32)(arow & 7) << 4;
  u32 kh2 = (u32)khe * 2u;
  int r0 = 32 * w + l15, r1 = r0 + 16;       // MFMA A rows == own-wave P rows
  u32 aswz = (u32)(l15 & 7) << 4;
  // DMA addressing: wave w stages B rows [40w,40w+40) in 5 chunks of 8 rows
  int rloc = l >> 3, slot = l & 7;
  u32 ldsw = (u32)__builtin_amdgcn_readfirstlane(w * 5120);

  uint4 pe[4];

  // ---- prologue: DMA B0 (tile 0) + e_j(0) prefetch ----
#pragma unroll
  for (int c = 0; c < 5; c++) {
    int r = 40 * w + 8 * c + rloc;
    const u16* g = wsim + (size_t)r * KP_ + ((slot ^ (r & 7)) * 8);
    gload_lds16(g, lds + LB0_ + ldsw + (u32)c * 1024u);
  }
#pragma unroll
  for (int q = 0; q < 4; q++) pe[q] = *(const uint4*)(ejrow + khe + q * 8);
  asm volatile("s_waitcnt vmcnt(4)" ::: "memory");   // 5 DMAs done; pe in flight
  __builtin_amdgcn_sched_barrier(0);
  __builtin_amdgcn_s_barrier();
  __builtin_amdgcn_sched_barrier(0);

  // ---- k-loop: ONE barrier per tile ----
  for (int kt = 0; kt < 20; kt++) {
    u32 bufr = (kt & 1) ? LB1_ : LB0_;
    u32 bufw = (kt & 1) ? LB0_ : LB1_;
    // (a) P-build(kt) into own-wave rows (consumes pe; compiler waits vmcnt)
    {
      const uint4* eis = (const uint4*)((const u16*)(lds + LEI_) + kt * 64 + khe);
#pragma unroll
      for (int q = 0; q < 4; q++) {
        uint4 ej = pe[q];
        uint4 ei = eis[q];
        const u32* pj = (const u32*)&ej;
        const u32* pi = (const u32*)&ei;
        u32 o[4];
#pragma unroll
        for (int c = 0; c < 4; c++)
          o[c] = cvtpk(bflo(pj[c]) * bflo(pi[c]), bfhi(pj[c]) * bfhi(pi[c]));
        *(uint4*)(lds + (pwr_base + ((kh2 + (u32)q * 16u) ^ pwr_swz))) = make_uint4(o[0], o[1], o[2], o[3]);
      }
    }
    // (b,c) issue next-tile DMA + e_j prefetch (in flight across MFMA + barrier)
    if (kt < 19) {
      int kn = (kt + 1) * 64;
#pragma unroll
      for (int c = 0; c < 5; c++) {
        int r = 40 * w + 8 * c + rloc;
        const u16* g = wsim + (size_t)r * KP_ + kn + ((slot ^ (r & 7)) * 8);
        gload_lds16(g, lds + bufw + ldsw + (u32)c * 1024u);
      }
#pragma unroll
      for (int q = 0; q < 4; q++) pe[q] = *(const uint4*)(ejrow + kn + khe + q * 8);
    }
    // fence P ds_writes before own-wave ds_reads (rule 18)
    asm volatile("s_waitcnt lgkmcnt(0)" ::: "memory");
    __builtin_amdgcn_sched_barrier(0);
    // (d) MFMA(kt): reads B[bufr] (barrier'd) + P (own-wave)
#pragma unroll
    for (int ks2 = 0; ks2 < 2; ks2++) {
      u32 inner = ((u32)(ks2 * 64 + oct * 16)) ^ aswz;
      short8v A0 = *(const short8v*)(lds + LP_ + (u32)r0 * 128u + inner);
      short8v A1 = *(const short8v*)(lds + LP_ + (u32)r1 * 128u + inner);
#pragma unroll
      for (int hf = 0; hf < 10; hf++) {
        short8v B = *(const short8v*)(lds + bufr + (u32)((hf * 16 + l15) * 128) + inner);
        acc[0][hf] = __builtin_amdgcn_mfma_f32_16x16x32_bf16(A0, B, acc[0][hf], 0, 0, 0);
        acc[1][hf] = __builtin_amdgcn_mfma_f32_16x16x32_bf16(A1, B, acc[1][hf], 0, 0, 0);
      }
    }
    // (e) own DMAs complete -> barrier (counted vmcnt: pe stays in flight)
    if (kt < 19) {
      asm volatile("s_waitcnt vmcnt(4)" ::: "memory");
      __builtin_amdgcn_sched_barrier(0);
      __builtin_amdgcn_s_barrier();
      __builtin_amdgcn_sched_barrier(0);
    }
  }

  // ---- finalize: h1 -> h1t bf16 swizzled (overlay [0,49152)) ----
  __syncthreads();
  for (int x = tid; x < 2048; x += 256) {
    int a = x >> 4, q = x & 15;
    u32 byte = 32768u + (u32)a * 128u + (((u32)(64 + q * 4)) ^ ((u32)(a & 7) << 4));
    *(u32*)(lds + byte) = 0u;
  }
  int mi = mspk[i];
#pragma unroll
  for (int hf = 0; hf < 10; hf++) {
    int h = hf * 16 + l15;
    float pmh = Pm[i * HP_ + h];
    float gbh = gb[h];
    int t = h >> 6, kkb = (h & 63) * 2;
#pragma unroll
    for (int p = 0; p < 2; p++) {
      int ab = (2 * w + p) * 16 + oct * 4;
#pragma unroll
      for (int r = 0; r < 4; r++) {
        int a = ab + r;
        int ju = jbase + a;
        int jr = min(ju, M_ - 1);
        int same = (mspk[jr] == mi) ? 1 : 0;
        int dist = min(max(i - ju, 0), 64);
        int bin = bins[dist];
        float v = acc[p][hf][r] + pmh + gbh + Pa[jr * HP_ + h]
                + spkc[same * HP_ + h] + dc[bin * HP_ + h];
        v = fmaxf(v, 0.f);
        u32 byte = (u32)t * 16384u + (u32)a * 128u + (((u32)kkb) ^ ((u32)(a & 7) << 4));
        *(u16*)(lds + byte) = f2bf(v);
      }
    }
  }
  __syncthreads();

  // ---- layer 2 via MFMA (K=192) ----
  float4v b2acc[2][10];
#pragma unroll
  for (int p = 0; p < 2; p++)
#pragma unroll
    for (int h = 0; h < 10; h++) b2acc[p][h] = (float4v)0.f;
#pragma unroll
  for (int t = 0; t < 3; t++) {
#pragma unroll
    for (int ks2 = 0; ks2 < 2; ks2++) {
      u32 inner = ((u32)(ks2 * 64 + oct * 16)) ^ aswz;
      u32 tb = (u32)t * 16384u;
      short8v A0 = *(const short8v*)(lds + tb + (u32)(32 * w + l15) * 128u + inner);
      short8v A1 = *(const short8v*)(lds + tb + (u32)(32 * w + 16 + l15) * 128u + inner);
      int ke = t * 64 + ks2 * 32 + oct * 8;
#pragma unroll
      for (int hf = 0; hf < 10; hf++) {
        short8v B = *(const short8v*)(w2a + (size_t)(hf * 16 + l15) * L2K_ + ke);
        b2acc[0][hf] = __builtin_amdgcn_mfma_f32_16x16x32_bf16(A0, B, b2acc[0][hf], 0, 0, 0);
        b2acc[1][hf] = __builtin_amdgcn_mfma_f32_16x16x32_bf16(A1, B, b2acc[1][hf], 0, 0, 0);
      }
    }
  }

  // ---- layer 3 + mask + mention scores ----
  float part[2][4] = {{0.f,0.f,0.f,0.f},{0.f,0.f,0.f,0.f}};
#pragma unroll
  for (int hf = 0; hf < 10; hf++) {
    int h = hf * 16 + l15;
    float bias = (h < HID_) ? ab2[h] : 0.f;
    float w3v  = (h < HID_) ? aw3[h] : 0.f;
#pragma unroll
    for (int p = 0; p < 2; p++)
#pragma unroll
      for (int r = 0; r < 4; r++) {
        float hv = fmaxf(b2acc[p][hf][r] + bias, 0.f);
        part[p][r] += hv * w3v;
      }
  }
#pragma unroll
  for (int m = 1; m <= 8; m <<= 1) {
#pragma unroll
    for (int p = 0; p < 2; p++)
#pragma unroll
      for (int r = 0; r < 4; r++) part[p][r] += __shfl_xor(part[p][r], m, 64);
  }
  float b3 = ab3[0];
  float msci = msc[i];
  if (l15 == 0) {
#pragma unroll
    for (int p = 0; p < 2; p++)
#pragma unroll
      for (int r = 0; r < 4; r++) {
        int a = (2 * w + p) * 16 + oct * 4 + r;
        if (a < A_) {
          float res = (a < len) ? (part[p][r] + b3 + msci + msc[jbase + a]) : NEGBIG_;
          out[(size_t)i * NCOL_ + 1 + a] = res;
        }
      }
  }
  if (tid == 0) out[(size_t)i * NCOL_] = 0.f;
}

extern "C" void kernel_launch(void* const* d_in, const int* in_sizes, int n_in,
                              void* d_out, int out_size, void* d_ws, size_t ws_size,
                              hipStream_t stream) {
  const float* doc   = (const float*)d_in[0];
  const float* lstm  = (const float*)d_in[1];
  const int*   cs    = (const int*)d_in[2];
  const int*   ce    = (const int*)d_in[3];
  const int*   tmi   = (const int*)d_in[4];
  const int*   spk   = (const int*)d_in[7];
  const int*   gid   = (const int*)d_in[8];
  const int*   bins  = (const int*)d_in[9];
  const float* wtab  = (const float*)d_in[10];
  const float* spkt  = (const float*)d_in[11];
  const float* gent  = (const float*)d_in[12];
  const float* distt = (const float*)d_in[13];
  const float* Wsp   = (const float*)d_in[14];
  const float* bsp   = (const float*)d_in[15];
  const float* msw1  = (const float*)d_in[16];
  const float* msb1  = (const float*)d_in[17];
  const float* msw2  = (const float*)d_in[18];
  const float* msb2  = (const float*)d_in[19];
  const float* msw3  = (const float*)d_in[20];
  const float* msb3  = (const float*)d_in[21];
  const float* asw1  = (const float*)d_in[22];
  const float* asb1  = (const float*)d_in[23];
  const float* asw2  = (const float*)d_in[24];
  const float* asb2  = (const float*)d_in[25];
  const float* asw3  = (const float*)d_in[26];
  const float* asb3  = (const float*)d_in[27];
  (void)in_sizes; (void)n_in; (void)out_size; (void)ws_size;

  char* ws = (char*)d_ws;
  float* msc   = (float*)(ws + OB_MSC);
  float* Pm    = (float*)(ws + OB_PM);
  float* Pa    = (float*)(ws + OB_PA);
  float* spkc  = (float*)(ws + OB_SPKC);
  float* gb    = (float*)(ws + OB_GB);
  float* dc    = (float*)(ws + OB_DC);
  int*   mspk  = (int*)(ws + OB_MSPK);
  float* h1w   = (float*)(ws + OB_H1W);
  u16*   mebf  = (u16*)(ws + OB_MEBF);
  u16*   wsim  = (u16*)(ws + OB_WSIM);
  u16*   wk2   = (u16*)(ws + OB_WK2);
  u16*   w2a   = (u16*)(ws + OB_W2A);
  float* out   = (float*)d_out;

  dim3 gb_(40, 5, 6);
  kb_prep<<<gb_, 256, 0, stream>>>(msw1, asw1, asw2, asb1, spkt, gent, distt, gid,
                                   wsim, wk2, w2a, spkc, gb, dc);
  ka_ment_emb<<<M_, 256, 0, stream>>>(doc, lstm, cs, ce, tmi, spk, wtab, Wsp, bsp,
                                      mebf, mspk);
  dim3 g2(5, 3);
  k2_mfma<<<g2, 256, 0, stream>>>(mebf, wk2, msb1, h1w, Pm, Pa);
  k5_msc<<<M_, 256, 0, stream>>>(h1w, msw2, msb2, msw3, msb3, msc);
  k4_pairs<<<M_, 256, 0, stream>>>(mebf, wsim, w2a, Pm, Pa, spkc, gb, dc,
                                   mspk, bins, msc, asb2, asw3, asb3, out);
}